// Round 6
// baseline (787.244 us; speedup 1.0000x reference)
//
#include <hip/hip_runtime.h>

#define INF 3.4e38f

// exact (value,index) insert with index tiebreak (used in merges only)
__device__ __forceinline__ void ins3t(float e, int ei,
                                      float& c0, float& c1, float& c2,
                                      int& i0, int& i1, int& i2)
{
    bool l0 = (e < c0) || (e == c0 && ei < i0);
    bool l1 = (e < c1) || (e == c1 && ei < i1);
    bool l2 = (e < c2) || (e == c2 && ei < i2);
    c2 = l1 ? c1 : (l2 ? e  : c2);
    i2 = l1 ? i1 : (l2 ? ei : i2);
    c1 = l0 ? c0 : (l1 ? e  : c1);
    i1 = l0 ? i0 : (l1 ? ei : i1);
    c0 = l0 ? e  : c0;
    i0 = l0 ? ei : i0;
}

// ---------------- Kernel A: KNN + IDW interp + Linear1 -> hT + BN stats ----------------
// Block = 256 thr = 64 vertices (4 threads/vertex, adjacent lanes).
// Centroids staged in LDS as (x,y,z,0.5|c|^2); med3-based top-3 scan.
__global__ __launch_bounds__(256) void fp_main(
    const float* __restrict__ verts,
    const float* __restrict__ cents,
    const float* __restrict__ feats,
    const float* __restrict__ W1,
    const float* __restrict__ b1,
    float* __restrict__ hT,
    float* __restrict__ gstats,
    int N, int M)
{
    __shared__ __align__(16) float4 pkS[2048];   // 32KB; reused as interpL after scan
    __shared__ int   widx[64][3];
    __shared__ float wwt [64][3];
    float* interpL = (float*)pkS;                // [64][65]

    int t = threadIdx.x, lane = t & 63;
    int cw = __builtin_amdgcn_readfirstlane((t >> 6) << 5);

    // stage + pack centroids
    for (int i = t; i < M; i += 256) {
        float x = cents[3*i], y = cents[3*i+1], z = cents[3*i+2];
        pkS[i] = make_float4(x, y, z, 0.5f * fmaf(x, x, fmaf(y, y, z*z)));
    }
    __syncthreads();

    int v0 = blockIdx.x * 64;
    int vloc = t >> 2, p = t & 3;
    int vtx = v0 + vloc;
    int vs  = vtx < N ? vtx : N - 1;
    float vx = verts[3*vs], vy = verts[3*vs+1], vz = verts[3*vs+2];

    // top-3 scan on s = 0.5|c|^2 - v.c (monotone with d^2); med3 value update
    float c0 = INF, c1 = INF, c2 = INF;
    int   i0 = 0x7fffffff, i1 = 0x7fffffff, i2 = 0x7fffffff;
    int q4 = M >> 2;
    const float4* cp = pkS + p;       // loop-invariant base; offsets become immediates
    #pragma unroll 8
    for (int i = 0; i < q4; ++i) {
        float4 c = cp[i << 2];
        float s = fmaf(-vx, c.x, fmaf(-vy, c.y, fmaf(-vz, c.z, c.w)));
        int m = p + (i << 2);
        bool l0 = s < c0, l1 = s < c1, l2 = s < c2;
        float n1 = __builtin_amdgcn_fmed3f(c0, c1, s);
        float n2 = __builtin_amdgcn_fmed3f(c1, c2, s);
        c0 = fminf(c0, s);
        i2 = l1 ? i1 : (l2 ? m : i2);
        i1 = l0 ? i0 : (l1 ? m : i1);
        i0 = l0 ? m  : i0;
        c1 = n1; c2 = n2;
    }
    // merge 4 partial lists (adjacent lanes, same wave)
    #pragma unroll
    for (int d = 1; d <= 2; d <<= 1) {
        float e0 = __shfl_xor(c0, d); int a0 = __shfl_xor(i0, d);
        float e1 = __shfl_xor(c1, d); int a1 = __shfl_xor(i1, d);
        float e2 = __shfl_xor(c2, d); int a2 = __shfl_xor(i2, d);
        ins3t(e0, a0, c0, c1, c2, i0, i1, i2);
        ins3t(e1, a1, c0, c1, c2, i0, i1, i2);
        ins3t(e2, a2, c0, c1, c2, i0, i1, i2);
    }

    if (p == 0) {
        // exact d^2 for winners; IDW weights (P=2 -> 1/d^2, no sqrt)
        float4 ca = pkS[i0], cb = pkS[i1], cc = pkS[i2];
        float dx, dy, dz;
        dx = vx-ca.x; dy = vy-ca.y; dz = vz-ca.z;
        float d0 = fmaf(dx,dx, fmaf(dy,dy, dz*dz));
        dx = vx-cb.x; dy = vy-cb.y; dz = vz-cb.z;
        float d1 = fmaf(dx,dx, fmaf(dy,dy, dz*dz));
        dx = vx-cc.x; dy = vy-cc.y; dz = vz-cc.z;
        float d2 = fmaf(dx,dx, fmaf(dy,dy, dz*dz));
        bool z0 = (d0 == 0.0f), z1 = (d1 == 0.0f), z2 = (d2 == 0.0f);
        float w0, w1, w2;
        if (z0 || z1 || z2) {
            w0 = z0 ? 1.0f : 0.0f;
            w1 = z1 ? 1.0f : 0.0f;
            w2 = z2 ? 1.0f : 0.0f;
        } else {
            w0 = 1.0f / d0; w1 = 1.0f / d1; w2 = 1.0f / d2;
        }
        float winv = 1.0f / (w0 + w1 + w2);
        widx[vloc][0] = i0; wwt[vloc][0] = w0 * winv;
        widx[vloc][1] = i1; wwt[vloc][1] = w1 * winv;
        widx[vloc][2] = i2; wwt[vloc][2] = w2 * winv;
    }
    __syncthreads();   // pkS reads done; widx/wwt published

    // gather: 4 threads/vertex, 16 feats each (overwrites pkS region)
    {
        int a0 = widx[vloc][0], a1 = widx[vloc][1], a2 = widx[vloc][2];
        float u0 = wwt[vloc][0], u1 = wwt[vloc][1], u2 = wwt[vloc][2];
        int fh = p * 16;
        const float4* f0 = (const float4*)(feats + (size_t)a0 * 64 + fh);
        const float4* f1 = (const float4*)(feats + (size_t)a1 * 64 + fh);
        const float4* f2 = (const float4*)(feats + (size_t)a2 * 64 + fh);
        float* dst = interpL + vloc * 65 + fh;
        #pragma unroll
        for (int q = 0; q < 4; ++q) {
            float4 A = f0[q], B = f1[q], C = f2[q];
            dst[4*q+0] = fmaf(u0, A.x, fmaf(u1, B.x, u2*C.x));
            dst[4*q+1] = fmaf(u0, A.y, fmaf(u1, B.y, u2*C.y));
            dst[4*q+2] = fmaf(u0, A.z, fmaf(u1, B.z, u2*C.z));
            dst[4*q+3] = fmaf(u0, A.w, fmaf(u1, B.w, u2*C.w));
        }
    }
    __syncthreads();

    // GEMM1: wave w -> cols [32w, 32w+32), lane -> vertex
    float acc[32];
    #pragma unroll
    for (int j = 0; j < 32; ++j) acc[j] = b1[cw + j];
    #pragma unroll 8
    for (int d = 0; d < 64; ++d) {
        float x = interpL[lane * 65 + d];
        const float* wr = W1 + d * 128 + cw;
        #pragma unroll
        for (int j = 0; j < 32; ++j) acc[j] = fmaf(x, wr[j], acc[j]);
    }
    int gv = v0 + lane;
    bool valid = gv < N;
    if (valid) {
        #pragma unroll
        for (int j = 0; j < 32; ++j)
            hT[(size_t)(cw + j) * N + gv] = acc[j];   // coalesced across lanes
    }
    // BN partial stats: reduce 64 vertices per channel, one atomic per channel
    #pragma unroll
    for (int j = 0; j < 32; ++j) {
        float v  = valid ? acc[j] : 0.0f;
        float vq = v * v;
        #pragma unroll
        for (int o = 32; o; o >>= 1) {
            v  += __shfl_xor(v, o);
            vq += __shfl_xor(vq, o);
        }
        if (lane == 0) {
            atomicAdd(&gstats[cw + j],       v);
            atomicAdd(&gstats[128 + cw + j], vq);
        }
    }
}

// ---------------- Kernel C: BN + ReLU + Linear2 ----------------
__global__ __launch_bounds__(256) void fp_bn_mlp2(
    const float* __restrict__ hT,
    const float* __restrict__ gstats,
    const float* __restrict__ gamma,
    const float* __restrict__ beta,
    const float* __restrict__ W2,
    const float* __restrict__ b2,
    float* __restrict__ out,
    int N)
{
    __shared__ float scS[128], shS[128];
    __shared__ __align__(16) float hl[128 * 68];   // phase2 reuse as [64][129]
    int t = threadIdx.x;
    if (t < 128) {
        float inv = 1.0f / (float)N;
        float mu  = gstats[t] * inv;
        float var = fmaf(-mu, mu, gstats[128 + t] * inv);
        var = fmaxf(var, 0.0f);
        float is = rsqrtf(var + 1e-5f);
        float sc = gamma[t] * is;
        scS[t] = sc;
        shS[t] = beta[t] - mu * sc;
    }
    __syncthreads();

    int r0 = blockIdx.x * 64;
    int N4 = N >> 2, r04 = r0 >> 2;
    const float4* hT4 = (const float4*)hT;

    // stage [128 ch][64 rows] with BN+ReLU applied, float4 loads
    #pragma unroll
    for (int jj = 0; jj < 8; ++jj) {
        int i4 = t + jj * 256;
        int k = i4 >> 4, r4 = i4 & 15;
        float4 v = make_float4(0.f, 0.f, 0.f, 0.f);
        if (r0 + 4*r4 < N) v = hT4[(size_t)k * N4 + r04 + r4];
        float sc = scS[k], sh = shS[k];
        float4 o;
        o.x = fmaxf(fmaf(v.x, sc, sh), 0.f);
        o.y = fmaxf(fmaf(v.y, sc, sh), 0.f);
        o.z = fmaxf(fmaf(v.z, sc, sh), 0.f);
        o.w = fmaxf(fmaf(v.w, sc, sh), 0.f);
        ((float4*)hl)[k * 17 + r4] = o;
    }
    __syncthreads();

    int lane = t & 63;
    int cw = __builtin_amdgcn_readfirstlane((t >> 6) << 5);
    float acc[32];
    #pragma unroll
    for (int j = 0; j < 32; ++j) acc[j] = b2[cw + j];
    #pragma unroll 4
    for (int k = 0; k < 128; ++k) {
        float x = hl[k * 68 + lane];
        const float* wr = W2 + k * 128 + cw;
        #pragma unroll
        for (int j = 0; j < 32; ++j) acc[j] = fmaf(x, wr[j], acc[j]);
    }
    __syncthreads();

    // transpose via LDS for coalesced float4 stores
    #pragma unroll
    for (int j = 0; j < 32; ++j) hl[lane * 129 + cw + j] = acc[j];
    __syncthreads();

    #pragma unroll
    for (int jj = 0; jj < 8; ++jj) {
        int i4 = t + jj * 256;
        int r = i4 >> 5, cq = (i4 & 31) << 2;
        int row = r0 + r;
        if (row < N) {
            float4 o4 = make_float4(hl[r*129 + cq],     hl[r*129 + cq + 1],
                                    hl[r*129 + cq + 2], hl[r*129 + cq + 3]);
            *(float4*)(out + (size_t)row * 128 + cq) = o4;
        }
    }
}

extern "C" void kernel_launch(void* const* d_in, const int* in_sizes, int n_in,
                              void* d_out, int out_size, void* d_ws, size_t ws_size,
                              hipStream_t stream)
{
    (void)n_in; (void)out_size; (void)ws_size;
    const float* verts = (const float*)d_in[0];
    const float* cents = (const float*)d_in[1];
    const float* feats = (const float*)d_in[2];
    const float* W1    = (const float*)d_in[3];
    const float* b1    = (const float*)d_in[4];
    const float* gamma = (const float*)d_in[5];
    const float* beta  = (const float*)d_in[6];
    const float* W2    = (const float*)d_in[7];
    const float* b2    = (const float*)d_in[8];
    float* out = (float*)d_out;

    int N = in_sizes[0] / 3;
    int M = in_sizes[1] / 3;

    float* gstats = (float*)d_ws;                    // 256 floats
    float* hT     = (float*)((char*)d_ws + 1024);    // [128, N]

    hipMemsetAsync(gstats, 0, 256 * sizeof(float), stream);

    int nblk = (N + 63) / 64;
    hipLaunchKernelGGL(fp_main, dim3(nblk), dim3(256), 0, stream,
                       verts, cents, feats, W1, b1, hT, gstats, N, M);

    hipLaunchKernelGGL(fp_bn_mlp2, dim3(nblk), dim3(256), 0, stream,
                       hT, gstats, gamma, beta, W2, b2, out, N);
}

// Round 7
// 363.758 us; speedup vs baseline: 2.1642x; 2.1642x over previous
//
#include <hip/hip_runtime.h>

#define INF 3.4e38f

// exact (value,index) insert with index tiebreak (used in merges only)
__device__ __forceinline__ void ins3t(float e, int ei,
                                      float& c0, float& c1, float& c2,
                                      int& i0, int& i1, int& i2)
{
    bool l0 = (e < c0) || (e == c0 && ei < i0);
    bool l1 = (e < c1) || (e == c1 && ei < i1);
    bool l2 = (e < c2) || (e == c2 && ei < i2);
    c2 = l1 ? c1 : (l2 ? e  : c2);
    i2 = l1 ? i1 : (l2 ? ei : i2);
    c1 = l0 ? c0 : (l1 ? e  : c1);
    i1 = l0 ? i0 : (l1 ? ei : i1);
    c0 = l0 ? e  : c0;
    i0 = l0 ? ei : i0;
}

// ---------------- Kernel A: KNN + IDW interp + Linear1 -> hT + partial BN stats ----------------
// Block = 256 thr = 64 vertices (4 threads/vertex, adjacent lanes).
// Centroids staged in LDS as (x,y,z,0.5|c|^2); med3-based top-3 scan.
// Stats: shuffle-reduce per wave, PLAIN stores to partials (no contended atomics).
__global__ __launch_bounds__(256) void fp_main(
    const float* __restrict__ verts,
    const float* __restrict__ cents,
    const float* __restrict__ feats,
    const float* __restrict__ W1,
    const float* __restrict__ b1,
    float* __restrict__ hT,
    float* __restrict__ partials,
    int N, int M)
{
    __shared__ __align__(16) float4 pkS[2048];   // 32KB; reused as interpL after scan
    __shared__ int   widx[64][3];
    __shared__ float wwt [64][3];
    float* interpL = (float*)pkS;                // [64][65]

    int t = threadIdx.x, lane = t & 63;
    int cw = __builtin_amdgcn_readfirstlane((t >> 6) << 5);

    // stage + pack centroids
    for (int i = t; i < M; i += 256) {
        float x = cents[3*i], y = cents[3*i+1], z = cents[3*i+2];
        pkS[i] = make_float4(x, y, z, 0.5f * fmaf(x, x, fmaf(y, y, z*z)));
    }
    __syncthreads();

    int v0 = blockIdx.x * 64;
    int vloc = t >> 2, p = t & 3;
    int vtx = v0 + vloc;
    int vs  = vtx < N ? vtx : N - 1;
    float vx = verts[3*vs], vy = verts[3*vs+1], vz = verts[3*vs+2];

    // top-3 scan on s = 0.5|c|^2 - v.c (monotone with d^2); med3 value update
    float c0 = INF, c1 = INF, c2 = INF;
    int   i0 = 0x7fffffff, i1 = 0x7fffffff, i2 = 0x7fffffff;
    int q4 = M >> 2;
    const float4* cp = pkS + p;
    #pragma unroll 8
    for (int i = 0; i < q4; ++i) {
        float4 c = cp[i << 2];
        float s = fmaf(-vx, c.x, fmaf(-vy, c.y, fmaf(-vz, c.z, c.w)));
        int m = p + (i << 2);
        bool l0 = s < c0, l1 = s < c1, l2 = s < c2;
        float n1 = __builtin_amdgcn_fmed3f(c0, c1, s);
        float n2 = __builtin_amdgcn_fmed3f(c1, c2, s);
        c0 = fminf(c0, s);
        i2 = l1 ? i1 : (l2 ? m : i2);
        i1 = l0 ? i0 : (l1 ? m : i1);
        i0 = l0 ? m  : i0;
        c1 = n1; c2 = n2;
    }
    // merge 4 partial lists (adjacent lanes, same wave)
    #pragma unroll
    for (int d = 1; d <= 2; d <<= 1) {
        float e0 = __shfl_xor(c0, d); int a0 = __shfl_xor(i0, d);
        float e1 = __shfl_xor(c1, d); int a1 = __shfl_xor(i1, d);
        float e2 = __shfl_xor(c2, d); int a2 = __shfl_xor(i2, d);
        ins3t(e0, a0, c0, c1, c2, i0, i1, i2);
        ins3t(e1, a1, c0, c1, c2, i0, i1, i2);
        ins3t(e2, a2, c0, c1, c2, i0, i1, i2);
    }

    if (p == 0) {
        // exact d^2 for winners; IDW weights (P=2 -> 1/d^2, no sqrt)
        float4 ca = pkS[i0], cb = pkS[i1], cc = pkS[i2];
        float dx, dy, dz;
        dx = vx-ca.x; dy = vy-ca.y; dz = vz-ca.z;
        float d0 = fmaf(dx,dx, fmaf(dy,dy, dz*dz));
        dx = vx-cb.x; dy = vy-cb.y; dz = vz-cb.z;
        float d1 = fmaf(dx,dx, fmaf(dy,dy, dz*dz));
        dx = vx-cc.x; dy = vy-cc.y; dz = vz-cc.z;
        float d2 = fmaf(dx,dx, fmaf(dy,dy, dz*dz));
        bool z0 = (d0 == 0.0f), z1 = (d1 == 0.0f), z2 = (d2 == 0.0f);
        float w0, w1, w2;
        if (z0 || z1 || z2) {
            w0 = z0 ? 1.0f : 0.0f;
            w1 = z1 ? 1.0f : 0.0f;
            w2 = z2 ? 1.0f : 0.0f;
        } else {
            w0 = 1.0f / d0; w1 = 1.0f / d1; w2 = 1.0f / d2;
        }
        float winv = 1.0f / (w0 + w1 + w2);
        widx[vloc][0] = i0; wwt[vloc][0] = w0 * winv;
        widx[vloc][1] = i1; wwt[vloc][1] = w1 * winv;
        widx[vloc][2] = i2; wwt[vloc][2] = w2 * winv;
    }
    __syncthreads();   // pkS reads done; widx/wwt published

    // gather: 4 threads/vertex, 16 feats each (overwrites pkS region)
    {
        int a0 = widx[vloc][0], a1 = widx[vloc][1], a2 = widx[vloc][2];
        float u0 = wwt[vloc][0], u1 = wwt[vloc][1], u2 = wwt[vloc][2];
        int fh = p * 16;
        const float4* f0 = (const float4*)(feats + (size_t)a0 * 64 + fh);
        const float4* f1 = (const float4*)(feats + (size_t)a1 * 64 + fh);
        const float4* f2 = (const float4*)(feats + (size_t)a2 * 64 + fh);
        float* dst = interpL + vloc * 65 + fh;
        #pragma unroll
        for (int q = 0; q < 4; ++q) {
            float4 A = f0[q], B = f1[q], C = f2[q];
            dst[4*q+0] = fmaf(u0, A.x, fmaf(u1, B.x, u2*C.x));
            dst[4*q+1] = fmaf(u0, A.y, fmaf(u1, B.y, u2*C.y));
            dst[4*q+2] = fmaf(u0, A.z, fmaf(u1, B.z, u2*C.z));
            dst[4*q+3] = fmaf(u0, A.w, fmaf(u1, B.w, u2*C.w));
        }
    }
    __syncthreads();

    // GEMM1: wave w -> cols [32w, 32w+32), lane -> vertex
    float acc[32];
    #pragma unroll
    for (int j = 0; j < 32; ++j) acc[j] = b1[cw + j];
    #pragma unroll 8
    for (int d = 0; d < 64; ++d) {
        float x = interpL[lane * 65 + d];
        const float* wr = W1 + d * 128 + cw;
        #pragma unroll
        for (int j = 0; j < 32; ++j) acc[j] = fmaf(x, wr[j], acc[j]);
    }
    int gv = v0 + lane;
    bool valid = gv < N;
    if (valid) {
        #pragma unroll
        for (int j = 0; j < 32; ++j)
            hT[(size_t)(cw + j) * N + gv] = acc[j];   // coalesced across lanes
    }
    // partial BN stats: shuffle-reduce 64 vertices/channel, plain store per block
    float* pout = partials + (size_t)blockIdx.x * 256;
    #pragma unroll
    for (int j = 0; j < 32; ++j) {
        float v  = valid ? acc[j] : 0.0f;
        float vq = v * v;
        #pragma unroll
        for (int o = 32; o; o >>= 1) {
            v  += __shfl_xor(v, o);
            vq += __shfl_xor(vq, o);
        }
        if (lane == 0) {
            pout[cw + j]       = v;
            pout[128 + cw + j] = vq;
        }
    }
}

// ---------------- Finalize: reduce partials -> BN scale/shift ----------------
__global__ __launch_bounds__(256) void fp_finalize(
    const float* __restrict__ partials,
    const float* __restrict__ gamma,
    const float* __restrict__ beta,
    float* __restrict__ ss, int nblk, int N)
{
    int t = threadIdx.x;
    float a0 = 0, a1 = 0, a2 = 0, a3 = 0;
    int i = 0;
    for (; i + 4 <= nblk; i += 4) {
        a0 += partials[(size_t)(i+0)*256 + t];
        a1 += partials[(size_t)(i+1)*256 + t];
        a2 += partials[(size_t)(i+2)*256 + t];
        a3 += partials[(size_t)(i+3)*256 + t];
    }
    for (; i < nblk; ++i) a0 += partials[(size_t)i*256 + t];
    __shared__ float sums[256];
    sums[t] = (a0 + a1) + (a2 + a3);
    __syncthreads();
    if (t < 128) {
        float inv = 1.0f / (float)N;
        float mu  = sums[t] * inv;
        float var = fmaf(-mu, mu, sums[128 + t] * inv);
        var = fmaxf(var, 0.0f);
        float is = rsqrtf(var + 1e-5f);
        float sc = gamma[t] * is;
        ss[t] = sc;
        ss[128 + t] = beta[t] - mu * sc;
    }
}

// ---------------- Kernel C: BN + ReLU + Linear2 ----------------
__global__ __launch_bounds__(256) void fp_bn_mlp2(
    const float* __restrict__ hT,
    const float* __restrict__ ss,
    const float* __restrict__ W2,
    const float* __restrict__ b2,
    float* __restrict__ out,
    int N)
{
    __shared__ float scS[128], shS[128];
    __shared__ __align__(16) float hl[128 * 68];   // phase2 reuse as [64][129]
    int t = threadIdx.x;
    if (t < 128) { scS[t] = ss[t]; shS[t] = ss[128 + t]; }
    __syncthreads();

    int r0 = blockIdx.x * 64;
    int N4 = N >> 2, r04 = r0 >> 2;
    const float4* hT4 = (const float4*)hT;

    // stage [128 ch][64 rows] with BN+ReLU applied, float4 loads
    #pragma unroll
    for (int jj = 0; jj < 8; ++jj) {
        int i4 = t + jj * 256;
        int k = i4 >> 4, r4 = i4 & 15;
        float4 v = make_float4(0.f, 0.f, 0.f, 0.f);
        if (r0 + 4*r4 < N) v = hT4[(size_t)k * N4 + r04 + r4];
        float sc = scS[k], sh = shS[k];
        float4 o;
        o.x = fmaxf(fmaf(v.x, sc, sh), 0.f);
        o.y = fmaxf(fmaf(v.y, sc, sh), 0.f);
        o.z = fmaxf(fmaf(v.z, sc, sh), 0.f);
        o.w = fmaxf(fmaf(v.w, sc, sh), 0.f);
        ((float4*)hl)[k * 17 + r4] = o;
    }
    __syncthreads();

    int lane = t & 63;
    int cw = __builtin_amdgcn_readfirstlane((t >> 6) << 5);
    float acc[32];
    #pragma unroll
    for (int j = 0; j < 32; ++j) acc[j] = b2[cw + j];
    #pragma unroll 4
    for (int k = 0; k < 128; ++k) {
        float x = hl[k * 68 + lane];
        const float* wr = W2 + k * 128 + cw;
        #pragma unroll
        for (int j = 0; j < 32; ++j) acc[j] = fmaf(x, wr[j], acc[j]);
    }
    __syncthreads();

    // transpose via LDS for coalesced float4 stores
    #pragma unroll
    for (int j = 0; j < 32; ++j) hl[lane * 129 + cw + j] = acc[j];
    __syncthreads();

    #pragma unroll
    for (int jj = 0; jj < 8; ++jj) {
        int i4 = t + jj * 256;
        int r = i4 >> 5, cq = (i4 & 31) << 2;
        int row = r0 + r;
        if (row < N) {
            float4 o4 = make_float4(hl[r*129 + cq],     hl[r*129 + cq + 1],
                                    hl[r*129 + cq + 2], hl[r*129 + cq + 3]);
            *(float4*)(out + (size_t)row * 128 + cq) = o4;
        }
    }
}

extern "C" void kernel_launch(void* const* d_in, const int* in_sizes, int n_in,
                              void* d_out, int out_size, void* d_ws, size_t ws_size,
                              hipStream_t stream)
{
    (void)n_in; (void)out_size; (void)ws_size;
    const float* verts = (const float*)d_in[0];
    const float* cents = (const float*)d_in[1];
    const float* feats = (const float*)d_in[2];
    const float* W1    = (const float*)d_in[3];
    const float* b1    = (const float*)d_in[4];
    const float* gamma = (const float*)d_in[5];
    const float* beta  = (const float*)d_in[6];
    const float* W2    = (const float*)d_in[7];
    const float* b2    = (const float*)d_in[8];
    float* out = (float*)d_out;

    int N = in_sizes[0] / 3;
    int M = in_sizes[1] / 3;

    float* ss       = (float*)d_ws;                    // 256 floats (scale/shift)
    float* hT       = (float*)((char*)d_ws + 1024);    // [128, N]
    float* partials = hT + (size_t)128 * N;            // [nblk, 256]

    int nblk = (N + 63) / 64;
    hipLaunchKernelGGL(fp_main, dim3(nblk), dim3(256), 0, stream,
                       verts, cents, feats, W1, b1, hT, partials, N, M);

    hipLaunchKernelGGL(fp_finalize, dim3(1), dim3(256), 0, stream,
                       partials, gamma, beta, ss, nblk, N);

    hipLaunchKernelGGL(fp_bn_mlp2, dim3(nblk), dim3(256), 0, stream,
                       hT, ss, W2, b2, out, N);
}

// Round 8
// 262.356 us; speedup vs baseline: 3.0007x; 1.3865x over previous
//
#include <hip/hip_runtime.h>

#define INF 3.4e38f
#define CHUNK 1024   // centroids per LDS chunk (16 KB)

// exact (value,index) insert with index tiebreak (used in merges only)
__device__ __forceinline__ void ins3t(float e, int ei,
                                      float& c0, float& c1, float& c2,
                                      int& i0, int& i1, int& i2)
{
    bool l0 = (e < c0) || (e == c0 && ei < i0);
    bool l1 = (e < c1) || (e == c1 && ei < i1);
    bool l2 = (e < c2) || (e == c2 && ei < i2);
    c2 = l1 ? c1 : (l2 ? e  : c2);
    i2 = l1 ? i1 : (l2 ? ei : i2);
    c1 = l0 ? c0 : (l1 ? e  : c1);
    i1 = l0 ? i0 : (l1 ? ei : i1);
    c0 = l0 ? e  : c0;
    i0 = l0 ? ei : i0;
}

// ---------------- Kernel A: KNN + IDW interp + Linear1 -> hT + partial BN stats ----------------
// Block = 256 thr = 64 vertices (4 threads/vertex). Centroids scanned in two
// 1024-entry LDS chunks (16.6KB LDS block -> 8 blocks/CU for latency hiding).
__global__ __launch_bounds__(256, 8) void fp_main(
    const float* __restrict__ verts,
    const float* __restrict__ cents,
    const float* __restrict__ feats,
    const float* __restrict__ W1,
    const float* __restrict__ b1,
    float* __restrict__ hT,
    float* __restrict__ partials,
    int N, int M)
{
    // aliased region: scan chunk float4[CHUNK] (16KB) / interpL [64][65] (16.64KB)
    __shared__ __align__(16) float smem[4160];
    __shared__ int   widx[64][3];
    __shared__ float wwt [64][3];
    float4* pkS     = (float4*)smem;
    float*  interpL = smem;

    int t = threadIdx.x, lane = t & 63;
    int cw = __builtin_amdgcn_readfirstlane((t >> 6) << 5);

    int v0 = blockIdx.x * 64;
    int vloc = t >> 2, p = t & 3;
    int vtx = v0 + vloc;
    int vs  = vtx < N ? vtx : N - 1;
    float vx = verts[3*vs], vy = verts[3*vs+1], vz = verts[3*vs+2];

    // top-3 scan on s = 0.5|c|^2 - v.c (monotone with d^2); med3 value update
    float c0 = INF, c1 = INF, c2 = INF;
    int   i0 = 0x7fffffff, i1 = 0x7fffffff, i2 = 0x7fffffff;

    for (int mb = 0; mb < M; mb += CHUNK) {
        int csz = M - mb; if (csz > CHUNK) csz = CHUNK;
        __syncthreads();   // previous chunk's reads (or interpL init) done
        for (int i = t; i < csz; i += 256) {
            int gm = mb + i;
            float x = cents[3*gm], y = cents[3*gm+1], z = cents[3*gm+2];
            pkS[i] = make_float4(x, y, z, 0.5f * fmaf(x, x, fmaf(y, y, z*z)));
        }
        __syncthreads();

        int q4 = csz >> 2;
        const float4* cp = pkS + p;
        #pragma unroll 8
        for (int i = 0; i < q4; ++i) {
            float4 c = cp[i << 2];
            float s = fmaf(-vx, c.x, fmaf(-vy, c.y, fmaf(-vz, c.z, c.w)));
            int m = mb + p + (i << 2);
            bool l0 = s < c0, l1 = s < c1, l2 = s < c2;
            float n1 = __builtin_amdgcn_fmed3f(c0, c1, s);
            float n2 = __builtin_amdgcn_fmed3f(c1, c2, s);
            c0 = fminf(c0, s);
            i2 = l1 ? i1 : (l2 ? m : i2);
            i1 = l0 ? i0 : (l1 ? m : i1);
            i0 = l0 ? m  : i0;
            c1 = n1; c2 = n2;
        }
    }

    // merge 4 partial lists (adjacent lanes, same wave)
    #pragma unroll
    for (int d = 1; d <= 2; d <<= 1) {
        float e0 = __shfl_xor(c0, d); int a0 = __shfl_xor(i0, d);
        float e1 = __shfl_xor(c1, d); int a1 = __shfl_xor(i1, d);
        float e2 = __shfl_xor(c2, d); int a2 = __shfl_xor(i2, d);
        ins3t(e0, a0, c0, c1, c2, i0, i1, i2);
        ins3t(e1, a1, c0, c1, c2, i0, i1, i2);
        ins3t(e2, a2, c0, c1, c2, i0, i1, i2);
    }

    if (p == 0) {
        // exact d^2 for winners from global cents (24KB, cache-hot)
        float ax = cents[3*i0], ay = cents[3*i0+1], az = cents[3*i0+2];
        float bx = cents[3*i1], by = cents[3*i1+1], bz = cents[3*i1+2];
        float cx = cents[3*i2], cy = cents[3*i2+1], cz = cents[3*i2+2];
        float dx, dy, dz;
        dx = vx-ax; dy = vy-ay; dz = vz-az;
        float d0 = fmaf(dx,dx, fmaf(dy,dy, dz*dz));
        dx = vx-bx; dy = vy-by; dz = vz-bz;
        float d1 = fmaf(dx,dx, fmaf(dy,dy, dz*dz));
        dx = vx-cx; dy = vy-cy; dz = vz-cz;
        float d2 = fmaf(dx,dx, fmaf(dy,dy, dz*dz));
        bool z0 = (d0 == 0.0f), z1 = (d1 == 0.0f), z2 = (d2 == 0.0f);
        float w0, w1, w2;
        if (z0 || z1 || z2) {
            w0 = z0 ? 1.0f : 0.0f;
            w1 = z1 ? 1.0f : 0.0f;
            w2 = z2 ? 1.0f : 0.0f;
        } else {
            w0 = 1.0f / d0; w1 = 1.0f / d1; w2 = 1.0f / d2;
        }
        float winv = 1.0f / (w0 + w1 + w2);
        widx[vloc][0] = i0; wwt[vloc][0] = w0 * winv;
        widx[vloc][1] = i1; wwt[vloc][1] = w1 * winv;
        widx[vloc][2] = i2; wwt[vloc][2] = w2 * winv;
    }
    __syncthreads();   // pkS reads done; widx/wwt published

    // gather: 4 threads/vertex, 16 feats each (overwrites scan chunk region)
    {
        int a0 = widx[vloc][0], a1 = widx[vloc][1], a2 = widx[vloc][2];
        float u0 = wwt[vloc][0], u1 = wwt[vloc][1], u2 = wwt[vloc][2];
        int fh = p * 16;
        const float4* f0 = (const float4*)(feats + (size_t)a0 * 64 + fh);
        const float4* f1 = (const float4*)(feats + (size_t)a1 * 64 + fh);
        const float4* f2 = (const float4*)(feats + (size_t)a2 * 64 + fh);
        float* dst = interpL + vloc * 65 + fh;
        #pragma unroll
        for (int q = 0; q < 4; ++q) {
            float4 A = f0[q], B = f1[q], C = f2[q];
            dst[4*q+0] = fmaf(u0, A.x, fmaf(u1, B.x, u2*C.x));
            dst[4*q+1] = fmaf(u0, A.y, fmaf(u1, B.y, u2*C.y));
            dst[4*q+2] = fmaf(u0, A.z, fmaf(u1, B.z, u2*C.z));
            dst[4*q+3] = fmaf(u0, A.w, fmaf(u1, B.w, u2*C.w));
        }
    }
    __syncthreads();

    // GEMM1: wave w -> cols [32w, 32w+32), lane -> vertex
    float acc[32];
    #pragma unroll
    for (int j = 0; j < 32; ++j) acc[j] = b1[cw + j];
    #pragma unroll 8
    for (int d = 0; d < 64; ++d) {
        float x = interpL[lane * 65 + d];
        const float* wr = W1 + d * 128 + cw;
        #pragma unroll
        for (int j = 0; j < 32; ++j) acc[j] = fmaf(x, wr[j], acc[j]);
    }
    int gv = v0 + lane;
    bool valid = gv < N;
    if (valid) {
        #pragma unroll
        for (int j = 0; j < 32; ++j)
            hT[(size_t)(cw + j) * N + gv] = acc[j];   // coalesced across lanes
    }
    // partial BN stats: shuffle-reduce 64 vertices/channel, plain store per block
    float* pout = partials + (size_t)blockIdx.x * 256;
    #pragma unroll
    for (int j = 0; j < 32; ++j) {
        float v  = valid ? acc[j] : 0.0f;
        float vq = v * v;
        #pragma unroll
        for (int o = 32; o; o >>= 1) {
            v  += __shfl_xor(v, o);
            vq += __shfl_xor(vq, o);
        }
        if (lane == 0) {
            pout[cw + j]       = v;
            pout[128 + cw + j] = vq;
        }
    }
}

// ---------------- Reduce partials -> gstats (64 blocks, low-contention atomics) ----------------
__global__ __launch_bounds__(256) void fp_reduce(
    const float* __restrict__ partials,
    float* __restrict__ gstats, int nblk)
{
    int t = threadIdx.x;
    int len = (nblk + gridDim.x - 1) / gridDim.x;
    int r0 = blockIdx.x * len;
    int r1 = r0 + len; if (r1 > nblk) r1 = nblk;
    float a0 = 0, a1 = 0, a2 = 0, a3 = 0;
    int i = r0;
    for (; i + 4 <= r1; i += 4) {
        a0 += partials[(size_t)(i+0)*256 + t];
        a1 += partials[(size_t)(i+1)*256 + t];
        a2 += partials[(size_t)(i+2)*256 + t];
        a3 += partials[(size_t)(i+3)*256 + t];
    }
    for (; i < r1; ++i) a0 += partials[(size_t)i*256 + t];
    atomicAdd(&gstats[t], (a0 + a1) + (a2 + a3));
}

// ---------------- Kernel C: BN + ReLU + Linear2 ----------------
__global__ __launch_bounds__(256) void fp_bn_mlp2(
    const float* __restrict__ hT,
    const float* __restrict__ gstats,
    const float* __restrict__ gamma,
    const float* __restrict__ beta,
    const float* __restrict__ W2,
    const float* __restrict__ b2,
    float* __restrict__ out,
    int N)
{
    __shared__ float scS[128], shS[128];
    __shared__ __align__(16) float hl[128 * 68];   // phase2 reuse as [64][129]
    int t = threadIdx.x;
    if (t < 128) {
        float inv = 1.0f / (float)N;
        float mu  = gstats[t] * inv;
        float var = fmaf(-mu, mu, gstats[128 + t] * inv);
        var = fmaxf(var, 0.0f);
        float is = rsqrtf(var + 1e-5f);
        float sc = gamma[t] * is;
        scS[t] = sc;
        shS[t] = beta[t] - mu * sc;
    }
    __syncthreads();

    int r0 = blockIdx.x * 64;
    int N4 = N >> 2, r04 = r0 >> 2;
    const float4* hT4 = (const float4*)hT;

    // stage [128 ch][64 rows] with BN+ReLU applied, float4 loads
    #pragma unroll
    for (int jj = 0; jj < 8; ++jj) {
        int i4 = t + jj * 256;
        int k = i4 >> 4, r4 = i4 & 15;
        float4 v = make_float4(0.f, 0.f, 0.f, 0.f);
        if (r0 + 4*r4 < N) v = hT4[(size_t)k * N4 + r04 + r4];
        float sc = scS[k], sh = shS[k];
        float4 o;
        o.x = fmaxf(fmaf(v.x, sc, sh), 0.f);
        o.y = fmaxf(fmaf(v.y, sc, sh), 0.f);
        o.z = fmaxf(fmaf(v.z, sc, sh), 0.f);
        o.w = fmaxf(fmaf(v.w, sc, sh), 0.f);
        ((float4*)hl)[k * 17 + r4] = o;
    }
    __syncthreads();

    int lane = t & 63;
    int cw = __builtin_amdgcn_readfirstlane((t >> 6) << 5);
    float acc[32];
    #pragma unroll
    for (int j = 0; j < 32; ++j) acc[j] = b2[cw + j];
    #pragma unroll 4
    for (int k = 0; k < 128; ++k) {
        float x = hl[k * 68 + lane];
        const float* wr = W2 + k * 128 + cw;
        #pragma unroll
        for (int j = 0; j < 32; ++j) acc[j] = fmaf(x, wr[j], acc[j]);
    }
    __syncthreads();

    // transpose via LDS for coalesced float4 stores
    #pragma unroll
    for (int j = 0; j < 32; ++j) hl[lane * 129 + cw + j] = acc[j];
    __syncthreads();

    #pragma unroll
    for (int jj = 0; jj < 8; ++jj) {
        int i4 = t + jj * 256;
        int r = i4 >> 5, cq = (i4 & 31) << 2;
        int row = r0 + r;
        if (row < N) {
            float4 o4 = make_float4(hl[r*129 + cq],     hl[r*129 + cq + 1],
                                    hl[r*129 + cq + 2], hl[r*129 + cq + 3]);
            *(float4*)(out + (size_t)row * 128 + cq) = o4;
        }
    }
}

extern "C" void kernel_launch(void* const* d_in, const int* in_sizes, int n_in,
                              void* d_out, int out_size, void* d_ws, size_t ws_size,
                              hipStream_t stream)
{
    (void)n_in; (void)out_size; (void)ws_size;
    const float* verts = (const float*)d_in[0];
    const float* cents = (const float*)d_in[1];
    const float* feats = (const float*)d_in[2];
    const float* W1    = (const float*)d_in[3];
    const float* b1    = (const float*)d_in[4];
    const float* gamma = (const float*)d_in[5];
    const float* beta  = (const float*)d_in[6];
    const float* W2    = (const float*)d_in[7];
    const float* b2    = (const float*)d_in[8];
    float* out = (float*)d_out;

    int N = in_sizes[0] / 3;
    int M = in_sizes[1] / 3;

    float* gstats   = (float*)d_ws;                    // 256 floats
    float* hT       = (float*)((char*)d_ws + 1024);    // [128, N]
    float* partials = hT + (size_t)128 * N;            // [nblk, 256]

    hipMemsetAsync(gstats, 0, 256 * sizeof(float), stream);

    int nblk = (N + 63) / 64;
    hipLaunchKernelGGL(fp_main, dim3(nblk), dim3(256), 0, stream,
                       verts, cents, feats, W1, b1, hT, partials, N, M);

    hipLaunchKernelGGL(fp_reduce, dim3(64), dim3(256), 0, stream,
                       partials, gstats, nblk);

    hipLaunchKernelGGL(fp_bn_mlp2, dim3(nblk), dim3(256), 0, stream,
                       hT, gstats, gamma, beta, W2, b2, out, N);
}